// Round 8
// baseline (277.057 us; speedup 1.0000x reference)
//
#include <hip/hip_runtime.h>
#include <hip/hip_bf16.h>

#define S_TOT 2720
#define NROWS 5440

// ---------------- down projection: t0[b,pos,c] = x[b,pos,:] @ w_down + b_down
__global__ void down_kernel(const float* __restrict__ x, const float* __restrict__ w,
                            const float* __restrict__ b, float* __restrict__ t0) {
    int id = blockIdx.x * 256 + threadIdx.x;     // B*2048*32 = 131072
    int c = id & 31;
    int r = id >> 5;
    const float* xr = x + (size_t)r * 128;
    float a0 = b[c], a1 = 0.f, a2 = 0.f, a3 = 0.f;
#pragma unroll
    for (int k = 0; k < 128; k += 4) {
        a0 += xr[k]     * w[(k)     * 32 + c];
        a1 += xr[k + 1] * w[(k + 1) * 32 + c];
        a2 += xr[k + 2] * w[(k + 2) * 32 + c];
        a3 += xr[k + 3] * w[(k + 3) * 32 + c];
    }
    t0[id] = (a0 + a1) + (a2 + a3);
}

// ---------------- conv (stride4,k4) + bias + BN + ELU
__global__ void conv_kernel(const float* __restrict__ in, float* __restrict__ pooled,
                            const float* __restrict__ cw, const float* __restrict__ cb,
                            const float* __restrict__ bg, const float* __restrict__ bb,
                            const float* __restrict__ bm, const float* __restrict__ bv,
                            int level, int in_bstride, int in_off, int Lout, int out_off,
                            int total) {
    int id = blockIdx.x * 256 + threadIdx.x;
    if (id >= total) return;
    int co = id & 31;
    int lo = (id >> 5) % Lout;
    int b  = id / (32 * Lout);
    const float* ib = in + (size_t)(b * in_bstride + in_off + lo * 4) * 32;
    const float* w  = cw + (size_t)(level * 32 + co) * 32 * 4;
    float acc0 = 0.f, acc1 = 0.f, acc2 = 0.f, acc3 = 0.f;
#pragma unroll
    for (int ci = 0; ci < 32; ++ci) {
        acc0 += ib[0 * 32 + ci] * w[ci * 4 + 0];
        acc1 += ib[1 * 32 + ci] * w[ci * 4 + 1];
        acc2 += ib[2 * 32 + ci] * w[ci * 4 + 2];
        acc3 += ib[3 * 32 + ci] * w[ci * 4 + 3];
    }
    float acc = ((acc0 + acc1) + (acc2 + acc3)) + cb[level * 32 + co];
    acc = (acc - bm[level * 32 + co]) * rsqrtf(bv[level * 32 + co] + 1e-5f)
          * bg[level * 32 + co] + bb[level * 32 + co];
    acc = acc > 0.f ? acc : expm1f(acc);
    pooled[(size_t)(b * 672 + out_off + lo) * 32 + co] = acc;
}

// ---------------- build h rows (copy x | pooled@w_up+b_up) fused with LN0. wave per row.
__global__ void build_ln_kernel(const float* __restrict__ x, const float* __restrict__ pooled,
                                const float* __restrict__ w_up, const float* __restrict__ b_up,
                                const float* __restrict__ g, const float* __restrict__ bta,
                                float* __restrict__ h) {
    int wave = threadIdx.x >> 6;
    int lane = threadIdx.x & 63;
    int row = blockIdx.x * 4 + wave;          // 5440 rows
    int b = row / S_TOT, s = row % S_TOT;
    float v0, v1;
    if (s < 2048) {
        const float* xr = x + (size_t)(b * 2048 + s) * 128;
        v0 = xr[lane]; v1 = xr[lane + 64];
    } else {
        int p = s - 2048;
        const float* pr = pooled + (size_t)(b * 672 + p) * 32;
        float a0 = b_up[lane], a1 = b_up[lane + 64];
        float a2 = 0.f, a3 = 0.f;
#pragma unroll
        for (int k = 0; k < 32; k += 2) {
            float p0 = pr[k], p1 = pr[k + 1];
            a0 += p0 * w_up[k * 128 + lane];
            a1 += p0 * w_up[k * 128 + lane + 64];
            a2 += p1 * w_up[(k + 1) * 128 + lane];
            a3 += p1 * w_up[(k + 1) * 128 + lane + 64];
        }
        v0 = a0 + a2; v1 = a1 + a3;
    }
    float sum = v0 + v1;
#pragma unroll
    for (int off = 32; off; off >>= 1) sum += __shfl_xor(sum, off);
    float mu = sum * (1.f / 128.f);
    float d0 = v0 - mu, d1 = v1 - mu;
    float vs = d0 * d0 + d1 * d1;
#pragma unroll
    for (int off = 32; off; off >>= 1) vs += __shfl_xor(vs, off);
    float inv = rsqrtf(vs * (1.f / 128.f) + 1e-5f);
    h[(size_t)row * 128 + lane]      = d0 * inv * g[lane]      + bta[lane];
    h[(size_t)row * 128 + lane + 64] = d1 * inv * g[lane + 64] + bta[lane + 64];
}

// ---------------- LayerNorm over 128 with residual. wave per row, 2 elems/lane. In-place safe.
__global__ void ln_kernel(const float* __restrict__ A, const float* __restrict__ R,
                          const float* __restrict__ g, const float* __restrict__ bta,
                          float* __restrict__ out, float eps) {
    int wave = threadIdx.x >> 6;
    int lane = threadIdx.x & 63;
    int row = blockIdx.x * 4 + wave;
    const float* a = A + (size_t)row * 128;
    float v0 = a[lane], v1 = a[lane + 64];
    const float* rr = R + (size_t)row * 128;
    v0 += rr[lane]; v1 += rr[lane + 64];
    float sum = v0 + v1;
#pragma unroll
    for (int off = 32; off; off >>= 1) sum += __shfl_xor(sum, off);
    float mu = sum * (1.f / 128.f);
    float d0 = v0 - mu, d1 = v1 - mu;
    float vs = d0 * d0 + d1 * d1;
#pragma unroll
    for (int off = 32; off; off >>= 1) vs += __shfl_xor(vs, off);
    float inv = rsqrtf(vs * (1.f / 128.f) + eps);
    out[(size_t)row * 128 + lane]      = d0 * inv * g[lane]      + bta[lane];
    out[(size_t)row * 128 + lane + 64] = d1 * inv * g[lane + 64] + bta[lane + 64];
}

// ---------------- QKV, lane=row scheme. 510 blocks = 85 row-tiles x 6 col-tiles(64).
// Lane owns one row; wave owns 16 cols; weights are wave-uniform -> SGPR loads.
__global__ __launch_bounds__(256) void qkv_rl(const float* __restrict__ H,
                                              const float* __restrict__ wq,
                                              const float* __restrict__ wk,
                                              const float* __restrict__ wv,
                                              float* __restrict__ q, float* __restrict__ k,
                                              float* __restrict__ v) {
    int tid = threadIdx.x;
    int jt = blockIdx.x % 6;
    int r0 = (blockIdx.x / 6) * 64;
    int lane = tid & 63;
    int row = r0 + lane;
    int jg = __builtin_amdgcn_readfirstlane(jt * 64 + (tid >> 6) * 16);
    const float* W = (jg < 128) ? wq : (jg < 256) ? wk : wv;
    float* O       = (jg < 128) ? q  : (jg < 256) ? k  : v;
    int j0 = jg & 127;
    const float* hrow = H + (size_t)row * 128;
    float acc[16];
#pragma unroll
    for (int jj = 0; jj < 16; ++jj) acc[jj] = 0.f;
    for (int kt = 0; kt < 128; kt += 4) {
        float4 hv = *(const float4*)(hrow + kt);
#pragma unroll
        for (int kk = 0; kk < 4; ++kk) {
            const float* wr = W + (size_t)(kt + kk) * 128 + j0;
            float hvv = ((const float*)&hv)[kk];
#pragma unroll
            for (int jj = 0; jj < 16; ++jj) acc[jj] += hvv * wr[jj];
        }
    }
    float* orow = O + (size_t)row * 128 + j0;
#pragma unroll
    for (int jj = 0; jj < 16; ++jj) orow[jj] = acc[jj];
}

// ---------------- sparse pyramid attention, 4 lanes per query (each owns 8 dims)
__global__ void attn_kernel(const float* __restrict__ Q, const float* __restrict__ K,
                            const float* __restrict__ V, float* __restrict__ O) {
    int id = blockIdx.x * 256 + threadIdx.x;     // 87040
    int d0 = (id & 3) * 8;
    int gid = id >> 2;                           // 21760 queries
    int i  = gid % S_TOT;
    int hh = (gid / S_TOT) & 3;
    int b  = gid / (S_TOT * 4);
    int li, s;
    if (i < 2048)      { li = 0; s = 0;    }
    else if (i < 2560) { li = 1; s = 2048; }
    else if (i < 2688) { li = 2; s = 2560; }
    else               { li = 3; s = 2688; }
    int sz = (li == 0) ? 2048 : (li == 1) ? 512 : (li == 2) ? 128 : 32;
    int pstart = (li == 0) ? 2048 : (li == 1) ? 2560 : 2688;
    int cstart = (li == 1) ? 0 : (li == 2) ? 2048 : 2560;

    const float* qp = Q + ((size_t)(b * S_TOT + i) * 128) + hh * 32 + d0;
    float4 qa = *(const float4*)qp;
    float4 qb = *(const float4*)(qp + 4);
    const float invt = 0.17677669529663687f;     // 1/sqrt(32)

    float sc[10];
    int   nj[10];
    bool  vl[10];
#pragma unroll
    for (int slot = 0; slot < 10; ++slot) {
        int j; bool valid;
        if (slot < 5)       { j = i - 2 + slot;                         valid = (j >= s) && (j < s + sz); }
        else if (slot == 5) { j = pstart + ((i - s) >> 2);              valid = (li < 3); }
        else                { j = cstart + ((i - s) << 2) + (slot - 6); valid = (li > 0); }
        nj[slot] = j; vl[slot] = valid;
        float dot = 0.f;
        if (valid) {
            const float* kp = K + ((size_t)(b * S_TOT + j) * 128) + hh * 32 + d0;
            float4 ka = *(const float4*)kp;
            float4 kb = *(const float4*)(kp + 4);
            dot = qa.x * ka.x + qa.y * ka.y + qa.z * ka.z + qa.w * ka.w
                + qb.x * kb.x + qb.y * kb.y + qb.z * kb.z + qb.w * kb.w;
        }
        dot += __shfl_xor(dot, 1);
        dot += __shfl_xor(dot, 2);
        sc[slot] = valid ? dot * invt : -1e30f;
    }
    float mx = sc[0];
#pragma unroll
    for (int slot = 1; slot < 10; ++slot) mx = fmaxf(mx, sc[slot]);
    float ssum = 0.f;
#pragma unroll
    for (int slot = 0; slot < 10; ++slot) { sc[slot] = __expf(sc[slot] - mx); ssum += sc[slot]; }
    float rinv = 1.f / ssum;
    float4 oa = {0.f, 0.f, 0.f, 0.f}, ob = {0.f, 0.f, 0.f, 0.f};
#pragma unroll
    for (int slot = 0; slot < 10; ++slot) {
        if (vl[slot]) {
            float p = sc[slot] * rinv;
            const float* vp = V + ((size_t)(b * S_TOT + nj[slot]) * 128) + hh * 32 + d0;
            float4 va = *(const float4*)vp;
            float4 vb = *(const float4*)(vp + 4);
            oa.x += p * va.x; oa.y += p * va.y; oa.z += p * va.z; oa.w += p * va.w;
            ob.x += p * vb.x; ob.y += p * vb.y; ob.z += p * vb.z; ob.w += p * vb.w;
        }
    }
    float* op = O + ((size_t)(b * S_TOT + i) * 128) + hh * 32 + d0;
    *(float4*)op = oa;
    *(float4*)(op + 4) = ob;
}

// ---------------- o-proj + residual + LN1. 340 blocks x 16 rows; wave owns 4 rows.
__global__ __launch_bounds__(256) void o_ln_kernel(const float* __restrict__ Ob,
                                                   const float* __restrict__ wo,
                                                   const float* __restrict__ g,
                                                   const float* __restrict__ bta,
                                                   float* __restrict__ h) {
    __shared__ float os[16][128];             // 8 KB
    int tid = threadIdx.x;
    int r0 = blockIdx.x * 16;                 // 340 blocks
    {
        const float4* src = (const float4*)(Ob + (size_t)r0 * 128);
        float4* dst = (float4*)os;
        dst[tid] = src[tid];
        dst[tid + 256] = src[tid + 256];
    }
    __syncthreads();
    int rbase = (tid >> 6) * 4, j0 = (tid & 63) * 2;
    float acc[4][2];
#pragma unroll
    for (int r = 0; r < 4; ++r) { acc[r][0] = 0.f; acc[r][1] = 0.f; }
    float2 wf[4], wfn[4];
#pragma unroll
    for (int kk = 0; kk < 4; ++kk) wf[kk] = *(const float2*)&wo[kk * 128 + j0];
    for (int kt = 0; kt < 128; kt += 4) {
        int ktn = (kt + 4) & 127;
#pragma unroll
        for (int kk = 0; kk < 4; ++kk) wfn[kk] = *(const float2*)&wo[(ktn + kk) * 128 + j0];
#pragma unroll
        for (int r = 0; r < 4; ++r) {
            float4 ha = *(const float4*)&os[rbase + r][kt];
            acc[r][0] += ha.x * wf[0].x; acc[r][1] += ha.x * wf[0].y;
            acc[r][0] += ha.y * wf[1].x; acc[r][1] += ha.y * wf[1].y;
            acc[r][0] += ha.z * wf[2].x; acc[r][1] += ha.z * wf[2].y;
            acc[r][0] += ha.w * wf[3].x; acc[r][1] += ha.w * wf[3].y;
        }
#pragma unroll
        for (int kk = 0; kk < 4; ++kk) wf[kk] = wfn[kk];
    }
    float g0 = g[j0], g1 = g[j0 + 1], bt0 = bta[j0], bt1 = bta[j0 + 1];
#pragma unroll
    for (int r = 0; r < 4; ++r) {
        size_t row = (size_t)(r0 + rbase + r) * 128;
        float2 res = *(const float2*)&h[row + j0];
        float v0 = acc[r][0] + res.x, v1 = acc[r][1] + res.y;
        float sum = v0 + v1;
#pragma unroll
        for (int off = 32; off; off >>= 1) sum += __shfl_xor(sum, off);
        float mu = sum * (1.f / 128.f);
        float e0 = v0 - mu, e1 = v1 - mu;
        float vs = e0 * e0 + e1 * e1;
#pragma unroll
        for (int off = 32; off; off >>= 1) vs += __shfl_xor(vs, off);
        float inv = rsqrtf(vs * (1.f / 128.f) + 1e-6f);
        *(float2*)&h[row + j0] = make_float2(e0 * inv * g0 + bt0, e1 * inv * g1 + bt1);
    }
}

// ---------------- FFN stage1, lane=row. 680 blocks = 85 row-tiles x 8 col-tiles(64).
// Writes relu(h@w1+b1) TRANSPOSED: f1t[j][row] (coalesced stores).
__global__ __launch_bounds__(256) void ffn1_rl(const float* __restrict__ H,
                                               const float* __restrict__ w1,
                                               const float* __restrict__ b1,
                                               float* __restrict__ f1t) {
    int tid = threadIdx.x;
    int jt = blockIdx.x & 7;
    int r0 = (blockIdx.x >> 3) * 64;
    int lane = tid & 63;
    int row = r0 + lane;
    int j0 = __builtin_amdgcn_readfirstlane(jt * 64 + (tid >> 6) * 16);
    const float* hrow = H + (size_t)row * 128;
    float acc[16];
#pragma unroll
    for (int jj = 0; jj < 16; ++jj) acc[jj] = 0.f;
    for (int kt = 0; kt < 128; kt += 4) {
        float4 hv = *(const float4*)(hrow + kt);
#pragma unroll
        for (int kk = 0; kk < 4; ++kk) {
            const float* wr = w1 + (size_t)(kt + kk) * 512 + j0;
            float hvv = ((const float*)&hv)[kk];
#pragma unroll
            for (int jj = 0; jj < 16; ++jj) acc[jj] += hvv * wr[jj];
        }
    }
#pragma unroll
    for (int jj = 0; jj < 16; ++jj)
        f1t[(size_t)(j0 + jj) * NROWS + row] = fmaxf(acc[jj] + b1[j0 + jj], 0.f);
}

// ---------------- FFN stage2, lane=row. 340 blocks = 85 row-tiles x 4 col-tiles(32).
// tmp[row][d] = f1t[:,row] @ w2[:,d] + b2[d]  (coalesced f1t loads)
__global__ __launch_bounds__(256) void ffn2_rl(const float* __restrict__ f1t,
                                               const float* __restrict__ w2,
                                               const float* __restrict__ b2,
                                               float* __restrict__ tmp) {
    int tid = threadIdx.x;
    int dt = blockIdx.x & 3;
    int r0 = (blockIdx.x >> 2) * 64;
    int lane = tid & 63;
    int row = r0 + lane;
    int d0 = __builtin_amdgcn_readfirstlane(dt * 32 + (tid >> 6) * 8);
    float acc[8];
#pragma unroll
    for (int dd = 0; dd < 8; ++dd) acc[dd] = 0.f;
#pragma unroll 4
    for (int j = 0; j < 512; ++j) {
        float fv = f1t[(size_t)j * NROWS + row];
        const float* wr = w2 + (size_t)j * 128 + d0;
#pragma unroll
        for (int dd = 0; dd < 8; ++dd) acc[dd] += fv * wr[dd];
    }
    float* trow = tmp + (size_t)row * 128 + d0;
#pragma unroll
    for (int dd = 0; dd < 8; ++dd) trow[dd] = acc[dd] + b2[d0 + dd];
}

// ---------------- gather refer-points, float4
__global__ void gather_kernel(const float* __restrict__ H, const int* __restrict__ idx,
                              float* __restrict__ out) {
    int id = blockIdx.x * 256 + threadIdx.x;     // 524288 float4s
    int d4 = id & 31;
    int j = (id >> 5) & 3;
    int t = (id >> 7) & 2047;
    int b = id >> 18;
    int src = idx[t * 4 + j];
    ((float4*)out)[id] = *(const float4*)&H[((size_t)(b * S_TOT + src) * 128) + d4 * 4];
}

extern "C" void kernel_launch(void* const* d_in, const int* in_sizes, int n_in,
                              void* d_out, int out_size, void* d_ws, size_t ws_size,
                              hipStream_t stream) {
    (void)in_sizes; (void)n_in; (void)out_size; (void)ws_size;
    const float* x       = (const float*)d_in[0];
    const float* w_down  = (const float*)d_in[1];
    const float* b_down  = (const float*)d_in[2];
    const float* conv_w  = (const float*)d_in[3];
    const float* conv_b  = (const float*)d_in[4];
    const float* bn_g    = (const float*)d_in[5];
    const float* bn_b    = (const float*)d_in[6];
    const float* bn_m    = (const float*)d_in[7];
    const float* bn_v    = (const float*)d_in[8];
    const float* w_up    = (const float*)d_in[9];
    const float* b_up    = (const float*)d_in[10];
    const float* ln0_g   = (const float*)d_in[11];
    const float* ln0_b   = (const float*)d_in[12];
    const float* wq      = (const float*)d_in[13];
    const float* wk      = (const float*)d_in[14];
    const float* wv      = (const float*)d_in[15];
    const float* wo      = (const float*)d_in[16];
    const float* ln1_g   = (const float*)d_in[17];
    const float* ln1_b   = (const float*)d_in[18];
    const float* ffn_w1  = (const float*)d_in[19];
    const float* ffn_b1  = (const float*)d_in[20];
    const float* ffn_w2  = (const float*)d_in[21];
    const float* ffn_b2  = (const float*)d_in[22];
    const float* ln2_g   = (const float*)d_in[23];
    const float* ln2_b   = (const float*)d_in[24];
    const int* indexes   = (const int*)d_in[26];

    float* ws = (float*)d_ws;
    float* t0     = ws;               // 131072
    float* pooled = ws + 131072;      // 43008
    float* h      = ws + 174080;      // 696320
    float* q      = ws + 870400;      // 696320
    float* k      = ws + 1566720;     // 696320
    float* v      = ws + 2263040;     // 696320
    float* o      = ws + 2959360;     // 696320
    float* f1t    = ws + 870400;      // 2785280 floats, overlays q/k/v/o (dead during FFN)
    float* tmp    = ws + 3655680;     // 696320

    down_kernel<<<512, 256, 0, stream>>>(x, w_down, b_down, t0);
    conv_kernel<<<128, 256, 0, stream>>>(t0, pooled, conv_w, conv_b, bn_g, bn_b, bn_m, bn_v,
                                         0, 2048, 0, 512, 0, 32768);
    conv_kernel<<<32, 256, 0, stream>>>(pooled, pooled, conv_w, conv_b, bn_g, bn_b, bn_m, bn_v,
                                        1, 672, 0, 128, 512, 8192);
    conv_kernel<<<8, 256, 0, stream>>>(pooled, pooled, conv_w, conv_b, bn_g, bn_b, bn_m, bn_v,
                                       2, 672, 512, 32, 640, 2048);
    build_ln_kernel<<<1360, 256, 0, stream>>>(x, pooled, w_up, b_up, ln0_g, ln0_b, h);

    for (int l = 0; l < 2; ++l) {
        qkv_rl<<<510, 256, 0, stream>>>(h, wq + l * 16384, wk + l * 16384, wv + l * 16384,
                                        q, k, v);
        attn_kernel<<<340, 256, 0, stream>>>(q, k, v, o);
        o_ln_kernel<<<340, 256, 0, stream>>>(o, wo + l * 16384,
                                             ln1_g + l * 128, ln1_b + l * 128, h);
        ffn1_rl<<<680, 256, 0, stream>>>(h, ffn_w1 + l * 65536, ffn_b1 + l * 512, f1t);
        ffn2_rl<<<340, 256, 0, stream>>>(f1t, ffn_w2 + l * 65536, ffn_b2 + l * 128, tmp);
        ln_kernel<<<1360, 256, 0, stream>>>(tmp, h, ln2_g + l * 128, ln2_b + l * 128, h, 1e-6f);
    }
    gather_kernel<<<2048, 256, 0, stream>>>(h, indexes, (float*)d_out);
}

// Round 10
// 179.678 us; speedup vs baseline: 1.5420x; 1.5420x over previous
//
#include <hip/hip_runtime.h>
#include <hip/hip_bf16.h>

#define S_TOT 2720

// ---------------- down projection: t0[b,pos,c] = x[b,pos,:] @ w_down + b_down
__global__ void down_kernel(const float* __restrict__ x, const float* __restrict__ w,
                            const float* __restrict__ b, float* __restrict__ t0) {
    int id = blockIdx.x * 256 + threadIdx.x;     // B*2048*32 = 131072
    int c = id & 31;
    int r = id >> 5;
    const float* xr = x + (size_t)r * 128;
    float a0 = b[c], a1 = 0.f, a2 = 0.f, a3 = 0.f;
#pragma unroll
    for (int k = 0; k < 128; k += 4) {
        a0 += xr[k]     * w[(k)     * 32 + c];
        a1 += xr[k + 1] * w[(k + 1) * 32 + c];
        a2 += xr[k + 2] * w[(k + 2) * 32 + c];
        a3 += xr[k + 3] * w[(k + 3) * 32 + c];
    }
    t0[id] = (a0 + a1) + (a2 + a3);
}

// ---------------- conv (stride4,k4) + bias + BN + ELU
__global__ void conv_kernel(const float* __restrict__ in, float* __restrict__ pooled,
                            const float* __restrict__ cw, const float* __restrict__ cb,
                            const float* __restrict__ bg, const float* __restrict__ bb,
                            const float* __restrict__ bm, const float* __restrict__ bv,
                            int level, int in_bstride, int in_off, int Lout, int out_off,
                            int total) {
    int id = blockIdx.x * 256 + threadIdx.x;
    if (id >= total) return;
    int co = id & 31;
    int lo = (id >> 5) % Lout;
    int b  = id / (32 * Lout);
    const float* ib = in + (size_t)(b * in_bstride + in_off + lo * 4) * 32;
    const float* w  = cw + (size_t)(level * 32 + co) * 32 * 4;
    float acc0 = 0.f, acc1 = 0.f, acc2 = 0.f, acc3 = 0.f;
#pragma unroll
    for (int ci = 0; ci < 32; ++ci) {
        acc0 += ib[0 * 32 + ci] * w[ci * 4 + 0];
        acc1 += ib[1 * 32 + ci] * w[ci * 4 + 1];
        acc2 += ib[2 * 32 + ci] * w[ci * 4 + 2];
        acc3 += ib[3 * 32 + ci] * w[ci * 4 + 3];
    }
    float acc = ((acc0 + acc1) + (acc2 + acc3)) + cb[level * 32 + co];
    acc = (acc - bm[level * 32 + co]) * rsqrtf(bv[level * 32 + co] + 1e-5f)
          * bg[level * 32 + co] + bb[level * 32 + co];
    acc = acc > 0.f ? acc : expm1f(acc);
    pooled[(size_t)(b * 672 + out_off + lo) * 32 + co] = acc;
}

// ---------------- build h rows (copy x | pooled@w_up+b_up) fused with LN0. wave per row.
__global__ void build_ln_kernel(const float* __restrict__ x, const float* __restrict__ pooled,
                                const float* __restrict__ w_up, const float* __restrict__ b_up,
                                const float* __restrict__ g, const float* __restrict__ bta,
                                float* __restrict__ h) {
    int wave = threadIdx.x >> 6;
    int lane = threadIdx.x & 63;
    int row = blockIdx.x * 4 + wave;          // 5440 rows
    int b = row / S_TOT, s = row % S_TOT;
    float v0, v1;
    if (s < 2048) {
        const float* xr = x + (size_t)(b * 2048 + s) * 128;
        v0 = xr[lane]; v1 = xr[lane + 64];
    } else {
        int p = s - 2048;
        const float* pr = pooled + (size_t)(b * 672 + p) * 32;
        float a0 = b_up[lane], a1 = b_up[lane + 64];
        float a2 = 0.f, a3 = 0.f;
#pragma unroll
        for (int k = 0; k < 32; k += 2) {
            float p0 = pr[k], p1 = pr[k + 1];
            a0 += p0 * w_up[k * 128 + lane];
            a1 += p0 * w_up[k * 128 + lane + 64];
            a2 += p1 * w_up[(k + 1) * 128 + lane];
            a3 += p1 * w_up[(k + 1) * 128 + lane + 64];
        }
        v0 = a0 + a2; v1 = a1 + a3;
    }
    float sum = v0 + v1;
#pragma unroll
    for (int off = 32; off; off >>= 1) sum += __shfl_xor(sum, off);
    float mu = sum * (1.f / 128.f);
    float d0 = v0 - mu, d1 = v1 - mu;
    float vs = d0 * d0 + d1 * d1;
#pragma unroll
    for (int off = 32; off; off >>= 1) vs += __shfl_xor(vs, off);
    float inv = rsqrtf(vs * (1.f / 128.f) + 1e-5f);
    h[(size_t)row * 128 + lane]      = d0 * inv * g[lane]      + bta[lane];
    h[(size_t)row * 128 + lane + 64] = d1 * inv * g[lane + 64] + bta[lane + 64];
}

// ---------------- QKV: grid = 170 row-tiles x 3 mats. Block: 32 rows, one weight matrix.
// Wave owns 8 rows; lane owns 2 cols; float2 weight loads + depth-1 prefetch.
__global__ __launch_bounds__(256) void qkv_kernel(const float* __restrict__ H,
                                                  const float* __restrict__ wq,
                                                  const float* __restrict__ wk,
                                                  const float* __restrict__ wv,
                                                  float* __restrict__ q, float* __restrict__ k,
                                                  float* __restrict__ v) {
    __shared__ float hs[32][128];             // 16 KB
    int tid = threadIdx.x;
    int mat = blockIdx.x % 3;
    int r0  = (blockIdx.x / 3) * 32;          // 170 row-tiles
    const float* W = (mat == 0) ? wq : (mat == 1) ? wk : wv;
    float* O       = (mat == 0) ? q  : (mat == 1) ? k  : v;
    {
        const float4* src = (const float4*)(H + (size_t)r0 * 128);
        float4* dst = (float4*)hs;
#pragma unroll
        for (int i = 0; i < 4; ++i) dst[tid + i * 256] = src[tid + i * 256];
    }
    __syncthreads();
    int rbase = (tid >> 6) * 8, j0 = (tid & 63) * 2;
    float acc[8][2];
#pragma unroll
    for (int r = 0; r < 8; ++r) { acc[r][0] = 0.f; acc[r][1] = 0.f; }
    float2 wf[4], wfn[4];
#pragma unroll
    for (int kk = 0; kk < 4; ++kk) wf[kk] = *(const float2*)&W[kk * 128 + j0];
    for (int kt = 0; kt < 128; kt += 4) {
        int ktn = (kt + 4) & 127;
#pragma unroll
        for (int kk = 0; kk < 4; ++kk) wfn[kk] = *(const float2*)&W[(ktn + kk) * 128 + j0];
#pragma unroll
        for (int r = 0; r < 8; ++r) {
            float4 ha = *(const float4*)&hs[rbase + r][kt];
            acc[r][0] += ha.x * wf[0].x; acc[r][1] += ha.x * wf[0].y;
            acc[r][0] += ha.y * wf[1].x; acc[r][1] += ha.y * wf[1].y;
            acc[r][0] += ha.z * wf[2].x; acc[r][1] += ha.z * wf[2].y;
            acc[r][0] += ha.w * wf[3].x; acc[r][1] += ha.w * wf[3].y;
        }
#pragma unroll
        for (int kk = 0; kk < 4; ++kk) wf[kk] = wfn[kk];
    }
#pragma unroll
    for (int r = 0; r < 8; ++r)
        *(float2*)&O[(size_t)(r0 + rbase + r) * 128 + j0] = make_float2(acc[r][0], acc[r][1]);
}

// ---------------- sparse pyramid attention, 4 lanes per query (each owns 8 dims)
__global__ void attn_kernel(const float* __restrict__ Q, const float* __restrict__ K,
                            const float* __restrict__ V, float* __restrict__ O) {
    int id = blockIdx.x * 256 + threadIdx.x;     // 87040
    int d0 = (id & 3) * 8;
    int gid = id >> 2;                           // 21760 queries
    int i  = gid % S_TOT;
    int hh = (gid / S_TOT) & 3;
    int b  = gid / (S_TOT * 4);
    int li, s;
    if (i < 2048)      { li = 0; s = 0;    }
    else if (i < 2560) { li = 1; s = 2048; }
    else if (i < 2688) { li = 2; s = 2560; }
    else               { li = 3; s = 2688; }
    int sz = (li == 0) ? 2048 : (li == 1) ? 512 : (li == 2) ? 128 : 32;
    int pstart = (li == 0) ? 2048 : (li == 1) ? 2560 : 2688;
    int cstart = (li == 1) ? 0 : (li == 2) ? 2048 : 2560;

    const float* qp = Q + ((size_t)(b * S_TOT + i) * 128) + hh * 32 + d0;
    float4 qa = *(const float4*)qp;
    float4 qb = *(const float4*)(qp + 4);
    const float invt = 0.17677669529663687f;     // 1/sqrt(32)

    float sc[10];
    int   nj[10];
    bool  vl[10];
#pragma unroll
    for (int slot = 0; slot < 10; ++slot) {
        int j; bool valid;
        if (slot < 5)       { j = i - 2 + slot;                         valid = (j >= s) && (j < s + sz); }
        else if (slot == 5) { j = pstart + ((i - s) >> 2);              valid = (li < 3); }
        else                { j = cstart + ((i - s) << 2) + (slot - 6); valid = (li > 0); }
        nj[slot] = j; vl[slot] = valid;
        float dot = 0.f;
        if (valid) {
            const float* kp = K + ((size_t)(b * S_TOT + j) * 128) + hh * 32 + d0;
            float4 ka = *(const float4*)kp;
            float4 kb = *(const float4*)(kp + 4);
            dot = qa.x * ka.x + qa.y * ka.y + qa.z * ka.z + qa.w * ka.w
                + qb.x * kb.x + qb.y * kb.y + qb.z * kb.z + qb.w * kb.w;
        }
        dot += __shfl_xor(dot, 1);
        dot += __shfl_xor(dot, 2);
        sc[slot] = valid ? dot * invt : -1e30f;
    }
    float mx = sc[0];
#pragma unroll
    for (int slot = 1; slot < 10; ++slot) mx = fmaxf(mx, sc[slot]);
    float ssum = 0.f;
#pragma unroll
    for (int slot = 0; slot < 10; ++slot) { sc[slot] = __expf(sc[slot] - mx); ssum += sc[slot]; }
    float rinv = 1.f / ssum;
    float4 oa = {0.f, 0.f, 0.f, 0.f}, ob = {0.f, 0.f, 0.f, 0.f};
#pragma unroll
    for (int slot = 0; slot < 10; ++slot) {
        if (vl[slot]) {
            float p = sc[slot] * rinv;
            const float* vp = V + ((size_t)(b * S_TOT + nj[slot]) * 128) + hh * 32 + d0;
            float4 va = *(const float4*)vp;
            float4 vb = *(const float4*)(vp + 4);
            oa.x += p * va.x; oa.y += p * va.y; oa.z += p * va.z; oa.w += p * va.w;
            ob.x += p * vb.x; ob.y += p * vb.y; ob.z += p * vb.z; ob.w += p * vb.w;
        }
    }
    float* op = O + ((size_t)(b * S_TOT + i) * 128) + hh * 32 + d0;
    *(float4*)op = oa;
    *(float4*)(op + 4) = ob;
}

// ---------------- o-proj + residual + LN1. 340 blocks x 16 rows; wave owns 4 rows.
__global__ __launch_bounds__(256) void o_ln_kernel(const float* __restrict__ Ob,
                                                   const float* __restrict__ wo,
                                                   const float* __restrict__ g,
                                                   const float* __restrict__ bta,
                                                   float* __restrict__ h) {
    __shared__ float os[16][128];             // 8 KB
    int tid = threadIdx.x;
    int r0 = blockIdx.x * 16;                 // 340 blocks
    {
        const float4* src = (const float4*)(Ob + (size_t)r0 * 128);
        float4* dst = (float4*)os;
        dst[tid] = src[tid];
        dst[tid + 256] = src[tid + 256];
    }
    __syncthreads();
    int rbase = (tid >> 6) * 4, j0 = (tid & 63) * 2;
    float acc[4][2];
#pragma unroll
    for (int r = 0; r < 4; ++r) { acc[r][0] = 0.f; acc[r][1] = 0.f; }
    float2 wf[4], wfn[4];
#pragma unroll
    for (int kk = 0; kk < 4; ++kk) wf[kk] = *(const float2*)&wo[kk * 128 + j0];
    for (int kt = 0; kt < 128; kt += 4) {
        int ktn = (kt + 4) & 127;
#pragma unroll
        for (int kk = 0; kk < 4; ++kk) wfn[kk] = *(const float2*)&wo[(ktn + kk) * 128 + j0];
#pragma unroll
        for (int r = 0; r < 4; ++r) {
            float4 ha = *(const float4*)&os[rbase + r][kt];
            acc[r][0] += ha.x * wf[0].x; acc[r][1] += ha.x * wf[0].y;
            acc[r][0] += ha.y * wf[1].x; acc[r][1] += ha.y * wf[1].y;
            acc[r][0] += ha.z * wf[2].x; acc[r][1] += ha.z * wf[2].y;
            acc[r][0] += ha.w * wf[3].x; acc[r][1] += ha.w * wf[3].y;
        }
#pragma unroll
        for (int kk = 0; kk < 4; ++kk) wf[kk] = wfn[kk];
    }
    float g0 = g[j0], g1 = g[j0 + 1], bt0 = bta[j0], bt1 = bta[j0 + 1];
#pragma unroll
    for (int r = 0; r < 4; ++r) {
        size_t row = (size_t)(r0 + rbase + r) * 128;
        float2 res = *(const float2*)&h[row + j0];
        float v0 = acc[r][0] + res.x, v1 = acc[r][1] + res.y;
        float sum = v0 + v1;
#pragma unroll
        for (int off = 32; off; off >>= 1) sum += __shfl_xor(sum, off);
        float mu = sum * (1.f / 128.f);
        float e0 = v0 - mu, e1 = v1 - mu;
        float vs = e0 * e0 + e1 * e1;
#pragma unroll
        for (int off = 32; off; off >>= 1) vs += __shfl_xor(vs, off);
        float inv = rsqrtf(vs * (1.f / 128.f) + 1e-6f);
        *(float2*)&h[row + j0] = make_float2(e0 * inv * g0 + bt0, e1 * inv * g1 + bt1);
    }
}

// ---------------- fused FFN + residual + LN2. 256 threads, 8 rows/block (measured-42us
// structure from R2) + depth-1 float2 weight prefetch. Correct strides: w1 row=512, w2 row=128.
__global__ __launch_bounds__(256) void ffn_kernel(const float* __restrict__ H,
                                                  const float* __restrict__ w1,
                                                  const float* __restrict__ b1,
                                                  const float* __restrict__ w2,
                                                  const float* __restrict__ b2,
                                                  const float* __restrict__ g,
                                                  const float* __restrict__ bta,
                                                  float* __restrict__ h) {
    __shared__ float hs[8][128];              // 4 KB
    __shared__ float f1s[8][512];             // 16 KB
    __shared__ float part[4][8][128];         // 16 KB
    int tid = threadIdx.x;
    int r0 = blockIdx.x * 8;                  // 680 blocks
    ((float4*)hs)[tid] = ((const float4*)(H + (size_t)r0 * 128))[tid];
    __syncthreads();
    // stage 1: thread owns cols j0, j0+1 of 512 (256 thr x 2 = 512 cols)
    {
        int j0 = tid * 2;
        float acc[8][2];
#pragma unroll
        for (int r = 0; r < 8; ++r) { acc[r][0] = 0.f; acc[r][1] = 0.f; }
        float2 wf[4], wfn[4];
#pragma unroll
        for (int kk = 0; kk < 4; ++kk) wf[kk] = *(const float2*)&w1[kk * 512 + j0];
        for (int kt = 0; kt < 128; kt += 4) {
            int ktn = (kt + 4) & 127;
#pragma unroll
            for (int kk = 0; kk < 4; ++kk) wfn[kk] = *(const float2*)&w1[(ktn + kk) * 512 + j0];
#pragma unroll
            for (int r = 0; r < 8; ++r) {
                float4 ha = *(const float4*)&hs[r][kt];
                acc[r][0] += ha.x * wf[0].x; acc[r][1] += ha.x * wf[0].y;
                acc[r][0] += ha.y * wf[1].x; acc[r][1] += ha.y * wf[1].y;
                acc[r][0] += ha.z * wf[2].x; acc[r][1] += ha.z * wf[2].y;
                acc[r][0] += ha.w * wf[3].x; acc[r][1] += ha.w * wf[3].y;
            }
#pragma unroll
            for (int kk = 0; kk < 4; ++kk) wf[kk] = wfn[kk];
        }
        float2 bv = *(const float2*)&b1[j0];
#pragma unroll
        for (int r = 0; r < 8; ++r)
            *(float2*)&f1s[r][j0] = make_float2(fmaxf(acc[r][0] + bv.x, 0.f),
                                                fmaxf(acc[r][1] + bv.y, 0.f));
    }
    __syncthreads();
    // stage 2: seg = tid>>6 (4 segs x 128 j's); thread owns d0 = (tid&63)*2
    {
        int seg = tid >> 6, d0 = (tid & 63) * 2, jb = seg * 128;
        float acc[8][2];
#pragma unroll
        for (int r = 0; r < 8; ++r) { acc[r][0] = 0.f; acc[r][1] = 0.f; }
        float2 wf[4], wfn[4];
#pragma unroll
        for (int jj = 0; jj < 4; ++jj) wf[jj] = *(const float2*)&w2[(size_t)(jb + jj) * 128 + d0];
        for (int jt = 0; jt < 128; jt += 4) {
            int jtn = (jt + 4) & 127;
#pragma unroll
            for (int jj = 0; jj < 4; ++jj)
                wfn[jj] = *(const float2*)&w2[(size_t)(jb + jtn + jj) * 128 + d0];
#pragma unroll
            for (int r = 0; r < 8; ++r) {
                float4 fa = *(const float4*)&f1s[r][jb + jt];
                acc[r][0] += fa.x * wf[0].x; acc[r][1] += fa.x * wf[0].y;
                acc[r][0] += fa.y * wf[1].x; acc[r][1] += fa.y * wf[1].y;
                acc[r][0] += fa.z * wf[2].x; acc[r][1] += fa.z * wf[2].y;
                acc[r][0] += fa.w * wf[3].x; acc[r][1] += fa.w * wf[3].y;
            }
#pragma unroll
            for (int jj = 0; jj < 4; ++jj) wf[jj] = wfn[jj];
        }
#pragma unroll
        for (int r = 0; r < 8; ++r)
            *(float2*)&part[seg][r][d0] = make_float2(acc[r][0], acc[r][1]);
    }
    __syncthreads();
    // final: combine segs + bias + residual + LN2. Row in 32 lanes x 4 vals (verified R1 block).
    {
        int r = tid >> 5, dgrp = tid & 31, d0 = dgrp * 4;
        float4 s0 = *(const float4*)&part[0][r][d0];
        float4 s1 = *(const float4*)&part[1][r][d0];
        float4 s2 = *(const float4*)&part[2][r][d0];
        float4 s3 = *(const float4*)&part[3][r][d0];
        float4 bb = *(const float4*)&b2[d0];
        size_t row = (size_t)(r0 + r) * 128;
        float4 res = *(const float4*)&h[row + d0];
        float v0 = s0.x + s1.x + s2.x + s3.x + bb.x + res.x;
        float v1 = s0.y + s1.y + s2.y + s3.y + bb.y + res.y;
        float v2 = s0.z + s1.z + s2.z + s3.z + bb.z + res.z;
        float v3 = s0.w + s1.w + s2.w + s3.w + bb.w + res.w;
        float sum = (v0 + v1) + (v2 + v3);
#pragma unroll
        for (int off = 16; off; off >>= 1) sum += __shfl_xor(sum, off);
        float mu = sum * (1.f / 128.f);
        float e0 = v0 - mu, e1 = v1 - mu, e2 = v2 - mu, e3 = v3 - mu;
        float vs = (e0 * e0 + e1 * e1) + (e2 * e2 + e3 * e3);
#pragma unroll
        for (int off = 16; off; off >>= 1) vs += __shfl_xor(vs, off);
        float inv = rsqrtf(vs * (1.f / 128.f) + 1e-6f);
        float4 gv = *(const float4*)&g[d0];
        float4 bv = *(const float4*)&bta[d0];
        float4 outv = make_float4(e0 * inv * gv.x + bv.x, e1 * inv * gv.y + bv.y,
                                  e2 * inv * gv.z + bv.z, e3 * inv * gv.w + bv.w);
        *(float4*)&h[row + d0] = outv;
    }
}

// ---------------- gather refer-points, float4
__global__ void gather_kernel(const float* __restrict__ H, const int* __restrict__ idx,
                              float* __restrict__ out) {
    int id = blockIdx.x * 256 + threadIdx.x;     // 524288 float4s
    int d4 = id & 31;
    int j = (id >> 5) & 3;
    int t = (id >> 7) & 2047;
    int b = id >> 18;
    int src = idx[t * 4 + j];
    ((float4*)out)[id] = *(const float4*)&H[((size_t)(b * S_TOT + src) * 128) + d4 * 4];
}

extern "C" void kernel_launch(void* const* d_in, const int* in_sizes, int n_in,
                              void* d_out, int out_size, void* d_ws, size_t ws_size,
                              hipStream_t stream) {
    (void)in_sizes; (void)n_in; (void)out_size; (void)ws_size;
    const float* x       = (const float*)d_in[0];
    const float* w_down  = (const float*)d_in[1];
    const float* b_down  = (const float*)d_in[2];
    const float* conv_w  = (const float*)d_in[3];
    const float* conv_b  = (const float*)d_in[4];
    const float* bn_g    = (const float*)d_in[5];
    const float* bn_b    = (const float*)d_in[6];
    const float* bn_m    = (const float*)d_in[7];
    const float* bn_v    = (const float*)d_in[8];
    const float* w_up    = (const float*)d_in[9];
    const float* b_up    = (const float*)d_in[10];
    const float* ln0_g   = (const float*)d_in[11];
    const float* ln0_b   = (const float*)d_in[12];
    const float* wq      = (const float*)d_in[13];
    const float* wk      = (const float*)d_in[14];
    const float* wv      = (const float*)d_in[15];
    const float* wo      = (const float*)d_in[16];
    const float* ln1_g   = (const float*)d_in[17];
    const float* ln1_b   = (const float*)d_in[18];
    const float* ffn_w1  = (const float*)d_in[19];
    const float* ffn_b1  = (const float*)d_in[20];
    const float* ffn_w2  = (const float*)d_in[21];
    const float* ffn_b2  = (const float*)d_in[22];
    const float* ln2_g   = (const float*)d_in[23];
    const float* ln2_b   = (const float*)d_in[24];
    const int* indexes   = (const int*)d_in[26];

    float* ws = (float*)d_ws;
    float* t0     = ws;               // 131072
    float* pooled = ws + 131072;      // 43008
    float* h      = ws + 174080;      // 696320
    float* q      = ws + 870400;      // 696320
    float* k      = ws + 1566720;     // 696320
    float* v      = ws + 2263040;     // 696320
    float* o      = ws + 2959360;     // 696320

    down_kernel<<<512, 256, 0, stream>>>(x, w_down, b_down, t0);
    conv_kernel<<<128, 256, 0, stream>>>(t0, pooled, conv_w, conv_b, bn_g, bn_b, bn_m, bn_v,
                                         0, 2048, 0, 512, 0, 32768);
    conv_kernel<<<32, 256, 0, stream>>>(pooled, pooled, conv_w, conv_b, bn_g, bn_b, bn_m, bn_v,
                                        1, 672, 0, 128, 512, 8192);
    conv_kernel<<<8, 256, 0, stream>>>(pooled, pooled, conv_w, conv_b, bn_g, bn_b, bn_m, bn_v,
                                       2, 672, 512, 32, 640, 2048);
    build_ln_kernel<<<1360, 256, 0, stream>>>(x, pooled, w_up, b_up, ln0_g, ln0_b, h);

    for (int l = 0; l < 2; ++l) {
        qkv_kernel<<<510, 256, 0, stream>>>(h, wq + l * 16384, wk + l * 16384, wv + l * 16384,
                                            q, k, v);
        attn_kernel<<<340, 256, 0, stream>>>(q, k, v, o);
        o_ln_kernel<<<340, 256, 0, stream>>>(o, wo + l * 16384,
                                             ln1_g + l * 128, ln1_b + l * 128, h);
        ffn_kernel<<<680, 256, 0, stream>>>(h, ffn_w1 + l * 65536, ffn_b1 + l * 512,
                                            ffn_w2 + l * 65536, ffn_b2 + l * 128,
                                            ln2_g + l * 128, ln2_b + l * 128, h);
    }
    gather_kernel<<<2048, 256, 0, stream>>>(h, indexes, (float*)d_out);
}